// Round 1
// baseline (3401.825 us; speedup 1.0000x reference)
//
#include <hip/hip_runtime.h>
#include <hip/hip_bf16.h>

#define D 128

typedef float f32x4  __attribute__((ext_vector_type(4)));
typedef float f32x16 __attribute__((ext_vector_type(16)));

// ---------------- CSR build ----------------
__global__ void k_hist(const int* __restrict__ edges, int E, int* __restrict__ deg) {
    int e = blockIdx.x * blockDim.x + threadIdx.x;
    if (e < E) {
        int a = edges[2 * e], b = edges[2 * e + 1];
        atomicAdd(&deg[a], 1);
        atomicAdd(&deg[b], 1);
    }
}

__global__ void k_scan1(const int* __restrict__ deg, int n,
                        int* __restrict__ incl, int* __restrict__ bsum) {
    __shared__ int lds[1024];
    int t = threadIdx.x;
    int i = blockIdx.x * 1024 + t;
    int v = (i < n) ? deg[i] : 0;
    int cur = v;
    lds[t] = cur;
    __syncthreads();
    for (int off = 1; off < 1024; off <<= 1) {
        int add = (t >= off) ? lds[t - off] : 0;
        __syncthreads();
        cur += add;
        lds[t] = cur;
        __syncthreads();
    }
    if (i < n) incl[i] = cur;
    if (t == 1023) bsum[blockIdx.x] = cur;
}

__global__ void k_scan2(int* __restrict__ bsum, int nb) {
    __shared__ int lds[128];
    int t = threadIdx.x;
    int v = (t < nb) ? bsum[t] : 0;
    int cur = v;
    lds[t] = cur;
    __syncthreads();
    for (int off = 1; off < 128; off <<= 1) {
        int add = (t >= off) ? lds[t - off] : 0;
        __syncthreads();
        cur += add;
        lds[t] = cur;
        __syncthreads();
    }
    if (t < nb) bsum[t] = cur - v;  // exclusive
}

__global__ void k_scan3(const int* __restrict__ incl, const int* __restrict__ deg,
                        const int* __restrict__ bsum, int n, int twoE,
                        int* __restrict__ rowstart, int* __restrict__ cursor) {
    int i = blockIdx.x * blockDim.x + threadIdx.x;
    if (i < n) {
        int r = incl[i] - deg[i] + bsum[i >> 10];
        rowstart[i] = r;
        cursor[i] = r;
    }
    if (i == 0) rowstart[n] = twoE;
}

__global__ void k_fill(const int* __restrict__ edges, int E,
                       int* __restrict__ cursor, int* __restrict__ adj) {
    int e = blockIdx.x * blockDim.x + threadIdx.x;
    if (e < E) {
        int a = edges[2 * e], b = edges[2 * e + 1];
        int pa = atomicAdd(&cursor[a], 1);
        adj[pa] = b;
        int pb = atomicAdd(&cursor[b], 1);
        adj[pb] = a;
    }
}

// ---------------- weight transpose: wt[l][m][k][o] ----------------
__global__ void k_transpose(const float* __restrict__ W0_1, const float* __restrict__ W1_1,
                            const float* __restrict__ W0_h, const float* __restrict__ W1_h,
                            float* __restrict__ wt) {
    int idx = blockIdx.x * 256 + threadIdx.x;
    if (idx >= 13 * 2 * 128 * 128) return;
    int o = idx & 127;
    int k = (idx >> 7) & 127;
    int m = (idx >> 14) & 1;
    int l = idx >> 15;
    const float* src = (l == 0) ? (m == 0 ? W0_1 : W1_1)
                                : ((m == 0 ? W0_h : W1_h) + (size_t)(l - 1) * 16384);
    wt[idx] = src[o * 128 + k];
}

// ---------------- neighbor aggregation: s[i] = sum_{j in adj(i)} x[j] ----------------
__global__ void k_agg(const float* __restrict__ x, const int* __restrict__ rowstart,
                      const int* __restrict__ adj, float* __restrict__ s, int n) {
    int i = blockIdx.x;
    int d = threadIdx.x;
    int r0 = rowstart[i], r1 = rowstart[i + 1];
    float acc = 0.f;
    for (int p = r0; p < r1; ++p) {
        int j = adj[p];
        acc += x[(size_t)j * D + d];
    }
    s[(size_t)i * D + d] = acc;
}

// ---------------- fused dual GEMM + bias + relu ----------------
// out[i][o] = act( x[i]·W0T[:,o] + s[i]·W1T[:,o] + b0[o] + deg[i]*b1[o] )
// lane = node (64/block), wave = 16-output slice (8 waves => 128 outputs)
__global__ __launch_bounds__(512, 4) void k_gemm(
    const float* __restrict__ x, const float* __restrict__ s,
    const float* __restrict__ wt,   // [2][128][128] transposed: [k][o]
    const float* __restrict__ b0, const float* __restrict__ b1,
    const int* __restrict__ deg, float* __restrict__ out,
    int n, int do_relu) {
    __shared__ float lds[2 * D * 64];   // 64 KB: x-tile [k][64], s-tile [k][64]
    float* xl = lds;
    float* sl = lds + D * 64;
    int t = threadIdx.x;
    int node0 = blockIdx.x * 64;

    // ---- stage x/s tiles into LDS transposed ([k][node]) ----
    {
        int nn = t & 63;        // node within tile
        int kg = t >> 6;        // 0..7 wave id => k-group
        int k0 = kg * 16;
        int g = node0 + nn;
        for (int q = 0; q < 4; ++q) {
            f32x4 xv = {0.f, 0.f, 0.f, 0.f}, sv = {0.f, 0.f, 0.f, 0.f};
            if (g < n) {
                xv = *(const f32x4*)&x[(size_t)g * D + k0 + q * 4];
                sv = *(const f32x4*)&s[(size_t)g * D + k0 + q * 4];
            }
            #pragma unroll
            for (int j = 0; j < 4; ++j) {
                xl[(k0 + q * 4 + j) * 64 + nn] = xv[j];
                sl[(k0 + q * 4 + j) * 64 + nn] = sv[j];
            }
        }
    }
    __syncthreads();

    int wave = __builtin_amdgcn_readfirstlane(t >> 6);
    int o0 = wave * 16;
    int lane = t & 63;
    int g = node0 + lane;
    const float* w0t = wt;
    const float* w1t = wt + D * D;

    float acc[16];
    #pragma unroll
    for (int j = 0; j < 16; ++j) acc[j] = 0.f;

    #pragma unroll 2
    for (int k = 0; k < D; ++k) {
        float xv = xl[k * 64 + lane];
        float sv = sl[k * 64 + lane];
        f32x16 w0 = *(const f32x16*)&w0t[k * D + o0];   // wave-uniform -> scalar loads
        f32x16 w1 = *(const f32x16*)&w1t[k * D + o0];
        #pragma unroll
        for (int j = 0; j < 16; ++j)
            acc[j] = __builtin_fmaf(sv, w1[j], __builtin_fmaf(xv, w0[j], acc[j]));
    }

    // ---- epilogue: bias + deg*b1 + relu ----
    f32x16 b0v = *(const f32x16*)&b0[o0];
    f32x16 b1v = *(const f32x16*)&b1[o0];
    float dg = (g < n) ? (float)deg[g] : 0.f;
    #pragma unroll
    for (int j = 0; j < 16; ++j) {
        float v = acc[j] + b0v[j] + dg * b1v[j];
        if (do_relu) v = fmaxf(v, 0.f);
        acc[j] = v;
    }

    // ---- transpose through LDS for coalesced stores ----
    __syncthreads();
    float* ol = lds;   // reuse, 32 KB
    #pragma unroll
    for (int j = 0; j < 16; ++j) ol[(o0 + j) * 64 + lane] = acc[j];
    __syncthreads();
    {
        int nn = t >> 3;          // 0..63
        int og = (t & 7) * 16;    // 8 groups x 16 = 128 outputs
        int g2 = node0 + nn;
        if (g2 < n) {
            #pragma unroll
            for (int q = 0; q < 4; ++q) {
                f32x4 v;
                #pragma unroll
                for (int j = 0; j < 4; ++j) v[j] = ol[(og + q * 4 + j) * 64 + nn];
                *(f32x4*)&out[(size_t)g2 * D + og + q * 4] = v;
            }
        }
    }
}

// ---------------- elementwise add (residual + aux) ----------------
__global__ void k_add(const float* __restrict__ a, const float* __restrict__ b,
                      float* __restrict__ c, int n4) {
    int i = blockIdx.x * blockDim.x + threadIdx.x;
    if (i < n4) {
        f32x4 va = ((const f32x4*)a)[i];
        f32x4 vb = ((const f32x4*)b)[i];
        ((f32x4*)c)[i] = va + vb;
    }
}

// ---------------- last layer (D_out = 3, no relu) ----------------
__global__ void k_last(const float* __restrict__ z, const float* __restrict__ sz,
                       const float* __restrict__ W0, const float* __restrict__ b0,
                       const float* __restrict__ W1, const float* __restrict__ b1,
                       const int* __restrict__ deg, float* __restrict__ vert, int n) {
    int t = threadIdx.x;
    int lane = t & 63;
    int node = blockIdx.x * 4 + (t >> 6);
    if (node >= n) return;
    float z0 = z[(size_t)node * D + lane], z1 = z[(size_t)node * D + 64 + lane];
    float s0 = sz[(size_t)node * D + lane], s1 = sz[(size_t)node * D + 64 + lane];
    float dg = (float)deg[node];
    #pragma unroll
    for (int o = 0; o < 3; ++o) {
        float p = z0 * W0[o * D + lane] + z1 * W0[o * D + 64 + lane]
                + s0 * W1[o * D + lane] + s1 * W1[o * D + 64 + lane];
        for (int off = 32; off > 0; off >>= 1) p += __shfl_down(p, off);
        if (lane == 0) vert[(size_t)node * 3 + o] = p + b0[o] + dg * b1[o];
    }
}

extern "C" void kernel_launch(void* const* d_in, const int* in_sizes, int n_in,
                              void* d_out, int out_size, void* d_ws, size_t ws_size,
                              hipStream_t stream) {
    const float* features = (const float*)d_in[0];
    const int*   edges    = (const int*)d_in[1];
    const float* W0_1 = (const float*)d_in[2];
    const float* b0_1 = (const float*)d_in[3];
    const float* W1_1 = (const float*)d_in[4];
    const float* b1_1 = (const float*)d_in[5];
    const float* W0_h = (const float*)d_in[6];
    const float* b0_h = (const float*)d_in[7];
    const float* W1_h = (const float*)d_in[8];
    const float* b1_h = (const float*)d_in[9];
    const float* W0_l = (const float*)d_in[10];
    const float* b0_l = (const float*)d_in[11];
    const float* W1_l = (const float*)d_in[12];
    const float* b1_l = (const float*)d_in[13];

    const int N_ = 100000, E_ = 300000;
    float* vert = (float*)d_out;              // N*3
    float* aux  = (float*)d_out + (size_t)N_ * 3;  // N*128

    char* w = (char*)d_ws;
    auto alloc = [&](size_t bytes) {
        char* p = w;
        w += (bytes + 255) & ~(size_t)255;
        return p;
    };
    float* wt    = (float*)alloc((size_t)13 * 2 * 128 * 128 * 4);
    float* resid = (float*)alloc((size_t)N_ * 128 * 4);
    float* xa    = (float*)alloc((size_t)N_ * 128 * 4);
    float* xb    = (float*)alloc((size_t)N_ * 128 * 4);
    float* sbuf  = (float*)alloc((size_t)N_ * 128 * 4);
    int* deg     = (int*)alloc((size_t)N_ * 4);
    int* incl    = (int*)alloc((size_t)N_ * 4);
    int* rowst   = (int*)alloc((size_t)(N_ + 1) * 4);
    int* cursor  = (int*)alloc((size_t)N_ * 4);
    int* bsum    = (int*)alloc(128 * 4);
    int* adj     = (int*)alloc((size_t)2 * E_ * 4);

    hipMemsetAsync(deg, 0, (size_t)N_ * 4, stream);
    k_hist<<<(E_ + 255) / 256, 256, 0, stream>>>(edges, E_, deg);
    int nb = (N_ + 1023) / 1024;   // 98
    k_scan1<<<nb, 1024, 0, stream>>>(deg, N_, incl, bsum);
    k_scan2<<<1, 128, 0, stream>>>(bsum, nb);
    k_scan3<<<(N_ + 255) / 256, 256, 0, stream>>>(incl, deg, bsum, N_, 2 * E_, rowst, cursor);
    k_fill<<<(E_ + 255) / 256, 256, 0, stream>>>(edges, E_, cursor, adj);
    k_transpose<<<(13 * 2 * 16384 + 255) / 256, 256, 0, stream>>>(W0_1, W1_1, W0_h, W1_h, wt);

    int gblocks = (N_ + 63) / 64;
    // layer 1: features -> resid
    k_agg<<<N_, 128, 0, stream>>>(features, rowst, adj, sbuf, N_);
    k_gemm<<<gblocks, 512, 0, stream>>>(features, sbuf, wt, b0_1, b1_1, deg, resid, N_, 1);
    // 12 hidden layers
    for (int h = 0; h < 12; ++h) {
        const float* in = (h == 0) ? resid : ((h & 1) ? xa : xb);
        float* outp = (h == 11) ? aux : ((h & 1) ? xb : xa);
        k_agg<<<N_, 128, 0, stream>>>(in, rowst, adj, sbuf, N_);
        k_gemm<<<gblocks, 512, 0, stream>>>(in, sbuf, wt + (size_t)(1 + h) * 2 * 16384,
                                            b0_h + h * 128, b1_h + h * 128, deg, outp, N_, 1);
    }
    // last layer: z = resid + aux; vertices = gconv(z) (no relu)
    k_add<<<(N_ * 32 + 255) / 256, 256, 0, stream>>>(resid, aux, xb, N_ * 32);
    k_agg<<<N_, 128, 0, stream>>>(xb, rowst, adj, sbuf, N_);
    k_last<<<(N_ + 3) / 4, 256, 0, stream>>>(xb, sbuf, W0_l, b0_l, W1_l, b1_l, deg, vert, N_);
}

// Round 2
// 1688.025 us; speedup vs baseline: 2.0153x; 2.0153x over previous
//
#include <hip/hip_runtime.h>
#include <hip/hip_bf16.h>

#define D 128

typedef float f32x4  __attribute__((ext_vector_type(4)));
typedef __attribute__((ext_vector_type(8))) __bf16 bh8;

__device__ inline float bf2f(unsigned short u) {
    union { unsigned int i; float f; } x; x.i = ((unsigned int)u) << 16; return x.f;
}
__device__ inline unsigned short f2bf(float f) {
    union { float f; unsigned int i; } x; x.f = f;
    return (unsigned short)((x.i + 0x7fffu + ((x.i >> 16) & 1u)) >> 16);
}

// ---------------- CSR build ----------------
__global__ void k_hist(const int* __restrict__ edges, int E, int* __restrict__ deg) {
    int e = blockIdx.x * blockDim.x + threadIdx.x;
    if (e < E) {
        atomicAdd(&deg[edges[2 * e]], 1);
        atomicAdd(&deg[edges[2 * e + 1]], 1);
    }
}

__global__ void k_scan1(const int* __restrict__ deg, int n,
                        int* __restrict__ incl, int* __restrict__ bsum) {
    __shared__ int lds[1024];
    int t = threadIdx.x;
    int i = blockIdx.x * 1024 + t;
    int v = (i < n) ? deg[i] : 0;
    int cur = v;
    lds[t] = cur;
    __syncthreads();
    for (int off = 1; off < 1024; off <<= 1) {
        int add = (t >= off) ? lds[t - off] : 0;
        __syncthreads();
        cur += add;
        lds[t] = cur;
        __syncthreads();
    }
    if (i < n) incl[i] = cur;
    if (t == 1023) bsum[blockIdx.x] = cur;
}

__global__ void k_scan2(int* __restrict__ bsum, int nb) {
    __shared__ int lds[128];
    int t = threadIdx.x;
    int v = (t < nb) ? bsum[t] : 0;
    int cur = v;
    lds[t] = cur;
    __syncthreads();
    for (int off = 1; off < 128; off <<= 1) {
        int add = (t >= off) ? lds[t - off] : 0;
        __syncthreads();
        cur += add;
        lds[t] = cur;
        __syncthreads();
    }
    if (t < nb) bsum[t] = cur - v;  // exclusive
}

__global__ void k_scan3(const int* __restrict__ incl, const int* __restrict__ deg,
                        const int* __restrict__ bsum, int n, int twoE,
                        int* __restrict__ rowstart, int* __restrict__ cursor) {
    int i = blockIdx.x * blockDim.x + threadIdx.x;
    if (i < n) {
        int r = incl[i] - deg[i] + bsum[i >> 10];
        rowstart[i] = r;
        cursor[i] = r;
    }
    if (i == 0) rowstart[n] = twoE;
}

__global__ void k_fill(const int* __restrict__ edges, int E,
                       int* __restrict__ cursor, int* __restrict__ adj) {
    int e = blockIdx.x * blockDim.x + threadIdx.x;
    if (e < E) {
        int a = edges[2 * e], b = edges[2 * e + 1];
        adj[atomicAdd(&cursor[a], 1)] = b;
        adj[atomicAdd(&cursor[b], 1)] = a;
    }
}

// ---------------- weight prep: bf16, K-chunked layout ----------------
// wb[l][chunk=kk>>5][o][kk&31], kk = m*128+k (m=0: W0, m=1: W1)
__global__ void k_wprep(const float* __restrict__ W0_1, const float* __restrict__ W1_1,
                        const float* __restrict__ W0_h, const float* __restrict__ W1_h,
                        unsigned short* __restrict__ wb) {
    int idx = blockIdx.x * 256 + threadIdx.x;
    if (idx >= 13 * 2 * 128 * 128) return;
    int k = idx & 127;
    int o = (idx >> 7) & 127;
    int m = (idx >> 14) & 1;
    int l = idx >> 15;
    const float* src = (l == 0) ? (m ? W1_1 : W0_1)
                                : ((m ? W1_h : W0_h) + (size_t)(l - 1) * 16384);
    float v = src[o * 128 + k];
    int kk = m * 128 + k;
    wb[(size_t)l * 32768 + (kk >> 5) * 4096 + o * 32 + (kk & 31)] = f2bf(v);
}

// ---------------- fp32 -> bf16 convert ----------------
__global__ void k_cvt(const float* __restrict__ in, unsigned short* __restrict__ out, int n4) {
    int i = blockIdx.x * blockDim.x + threadIdx.x;
    if (i >= n4) return;
    f32x4 v = *(const f32x4*)&in[(size_t)i * 4];
    unsigned short u[4];
    #pragma unroll
    for (int j = 0; j < 4; ++j) u[j] = f2bf(v[j]);
    *(uint2*)&out[(size_t)i * 4] = *(uint2*)u;
}

// ---------------- bf16 add: c = a + b ----------------
__global__ void k_addb(const unsigned short* __restrict__ a, const unsigned short* __restrict__ b,
                       unsigned short* __restrict__ c, int n2) {
    int i = blockIdx.x * blockDim.x + threadIdx.x;
    if (i >= n2) return;
    unsigned int ua = ((const unsigned int*)a)[i];
    unsigned int ub = ((const unsigned int*)b)[i];
    union { unsigned int i; float f; } la, ha, lb, hb;
    la.i = ua << 16; ha.i = ua & 0xffff0000u;
    lb.i = ub << 16; hb.i = ub & 0xffff0000u;
    unsigned int out = ((unsigned int)f2bf(ha.f + hb.f) << 16) | f2bf(la.f + lb.f);
    ((unsigned int*)c)[i] = out;
}

// ---------------- neighbor aggregation (bf16 in/out, fp32 accum) ----------------
__global__ __launch_bounds__(256) void k_agg(
    const unsigned short* __restrict__ x, const int* __restrict__ rowstart,
    const int* __restrict__ adj, unsigned short* __restrict__ s, int n) {
    int node = blockIdx.x * 4 + (threadIdx.x >> 6);
    int lane = threadIdx.x & 63;
    if (node >= n) return;
    int r0 = rowstart[node], r1 = rowstart[node + 1];
    float a0 = 0.f, a1 = 0.f;
    for (int p = r0; p < r1; ++p) {
        int j = adj[p];
        unsigned int u = *(const unsigned int*)&x[(size_t)j * D + lane * 2];
        union { unsigned int i; float f; } lo, hi;
        lo.i = u << 16; hi.i = u & 0xffff0000u;
        a0 += lo.f; a1 += hi.f;
    }
    unsigned int out = ((unsigned int)f2bf(a1) << 16) | f2bf(a0);
    *(unsigned int*)&s[(size_t)node * D + lane * 2] = out;
}

// ---------------- MFMA GEMM: out[i][o] = act([x_i, s_i] @ [W0T;W1T] + b0 + deg*b1) ----------------
// 256 threads = 4 waves; block tile 128 nodes x 128 outs; K=256 in 8 chunks of 32.
#define ASTR 40
__global__ __launch_bounds__(256) void k_gemm(
    const unsigned short* __restrict__ x,   // [n][128] bf16
    const unsigned short* __restrict__ s,   // [n][128] bf16
    const unsigned short* __restrict__ wb,  // layer weights, chunked [8][128][32] bf16
    const float* __restrict__ b0, const float* __restrict__ b1,
    const int* __restrict__ deg,
    unsigned short* __restrict__ out,       // [n][128] bf16
    float* __restrict__ out32,              // optional fp32 copy (aux), may be null
    int n, int do_relu) {
    __shared__ __align__(16) unsigned short Alds[128 * ASTR];  // 10240 B
    __shared__ __align__(16) unsigned short Blds[128 * ASTR];  // 10240 B
    int t = threadIdx.x;
    int node0 = blockIdx.x * 128;

    f32x4 acc[4][4];
    #pragma unroll
    for (int i = 0; i < 4; ++i)
        #pragma unroll
        for (int j = 0; j < 4; ++j) acc[i][j] = (f32x4){0.f, 0.f, 0.f, 0.f};

    int lane = t & 63;
    int wave = t >> 6;
    int wm = (wave & 1) * 64;
    int wn = (wave >> 1) * 64;
    int mlane = lane & 15;
    int quad = lane >> 4;

    for (int kc = 0; kc < 8; ++kc) {
        __syncthreads();
        // stage A chunk: 128 rows x 32 k (bf16) = 8 KB; fully coalesced 16B/thread x2
        const unsigned short* srcA = (kc < 4) ? x : s;
        int kbase = (kc & 3) * 32;
        #pragma unroll
        for (int p = 0; p < 2; ++p) {
            int c = p * 256 + t;
            int row = c >> 2;
            int seg = (c & 3) * 8;
            int g = node0 + row;
            uint4 v = {0u, 0u, 0u, 0u};
            if (g < n) v = *(const uint4*)&srcA[(size_t)g * D + kbase + seg];
            *(uint4*)&Alds[row * ASTR + seg] = v;
        }
        // stage B chunk: pre-chunked global layout -> linear coalesced copy
        const unsigned short* srcB = wb + (size_t)kc * 4096;
        #pragma unroll
        for (int p = 0; p < 2; ++p) {
            int c = p * 256 + t;
            int o = c >> 2;
            int seg = (c & 3) * 8;
            *(uint4*)&Blds[o * ASTR + seg] = *(const uint4*)&srcB[c * 8];
        }
        __syncthreads();

        bh8 af[4], bf[4];
        #pragma unroll
        for (int i = 0; i < 4; ++i)
            af[i] = *(const bh8*)&Alds[(wm + i * 16 + mlane) * ASTR + quad * 8];
        #pragma unroll
        for (int j = 0; j < 4; ++j)
            bf[j] = *(const bh8*)&Blds[(wn + j * 16 + mlane) * ASTR + quad * 8];
        #pragma unroll
        for (int i = 0; i < 4; ++i)
            #pragma unroll
            for (int j = 0; j < 4; ++j)
                acc[i][j] = __builtin_amdgcn_mfma_f32_16x16x32_bf16(af[i], bf[j], acc[i][j], 0, 0, 0);
    }

    // epilogue: bias + deg*b1 + relu, direct stores
    #pragma unroll
    for (int i = 0; i < 4; ++i) {
        int m = wm + i * 16 + quad * 4;
        #pragma unroll
        for (int j = 0; j < 4; ++j) {
            int nn = wn + j * 16 + mlane;
            float b0v = b0[nn], b1v = b1[nn];
            #pragma unroll
            for (int r = 0; r < 4; ++r) {
                int g = node0 + m + r;
                if (g < n) {
                    float dg = (float)deg[g];
                    float val = acc[i][j][r] + b0v + dg * b1v;
                    if (do_relu) val = fmaxf(val, 0.f);
                    out[(size_t)g * D + nn] = f2bf(val);
                    if (out32) out32[(size_t)g * D + nn] = val;
                }
            }
        }
    }
}

// ---------------- last layer (D_out = 3, fp32 out, no relu) ----------------
__global__ void k_last(const unsigned short* __restrict__ z, const unsigned short* __restrict__ sz,
                       const float* __restrict__ W0, const float* __restrict__ b0,
                       const float* __restrict__ W1, const float* __restrict__ b1,
                       const int* __restrict__ deg, float* __restrict__ vert, int n) {
    int t = threadIdx.x;
    int lane = t & 63;
    int node = blockIdx.x * 4 + (t >> 6);
    if (node >= n) return;
    float z0 = bf2f(z[(size_t)node * D + lane]), z1 = bf2f(z[(size_t)node * D + 64 + lane]);
    float s0 = bf2f(sz[(size_t)node * D + lane]), s1 = bf2f(sz[(size_t)node * D + 64 + lane]);
    float dg = (float)deg[node];
    #pragma unroll
    for (int o = 0; o < 3; ++o) {
        float p = z0 * W0[o * D + lane] + z1 * W0[o * D + 64 + lane]
                + s0 * W1[o * D + lane] + s1 * W1[o * D + 64 + lane];
        for (int off = 32; off > 0; off >>= 1) p += __shfl_down(p, off);
        if (lane == 0) vert[(size_t)node * 3 + o] = p + b0[o] + dg * b1[o];
    }
}

extern "C" void kernel_launch(void* const* d_in, const int* in_sizes, int n_in,
                              void* d_out, int out_size, void* d_ws, size_t ws_size,
                              hipStream_t stream) {
    const float* features = (const float*)d_in[0];
    const int*   edges    = (const int*)d_in[1];
    const float* W0_1 = (const float*)d_in[2];
    const float* b0_1 = (const float*)d_in[3];
    const float* W1_1 = (const float*)d_in[4];
    const float* b1_1 = (const float*)d_in[5];
    const float* W0_h = (const float*)d_in[6];
    const float* b0_h = (const float*)d_in[7];
    const float* W1_h = (const float*)d_in[8];
    const float* b1_h = (const float*)d_in[9];
    const float* W0_l = (const float*)d_in[10];
    const float* b0_l = (const float*)d_in[11];
    const float* W1_l = (const float*)d_in[12];
    const float* b1_l = (const float*)d_in[13];

    const int N_ = 100000, E_ = 300000;
    float* vert = (float*)d_out;                    // N*3
    float* aux  = (float*)d_out + (size_t)N_ * 3;   // N*128 fp32

    char* w = (char*)d_ws;
    auto alloc = [&](size_t bytes) {
        char* p = w;
        w += (bytes + 255) & ~(size_t)255;
        return p;
    };
    unsigned short* wb    = (unsigned short*)alloc((size_t)13 * 32768 * 2);
    unsigned short* xf    = (unsigned short*)alloc((size_t)N_ * D * 2);
    unsigned short* resid = (unsigned short*)alloc((size_t)N_ * D * 2);
    unsigned short* xa    = (unsigned short*)alloc((size_t)N_ * D * 2);
    unsigned short* xb    = (unsigned short*)alloc((size_t)N_ * D * 2);
    unsigned short* sb    = (unsigned short*)alloc((size_t)N_ * D * 2);
    int* deg    = (int*)alloc((size_t)N_ * 4);
    int* incl   = (int*)alloc((size_t)N_ * 4);
    int* rowst  = (int*)alloc((size_t)(N_ + 1) * 4);
    int* cursor = (int*)alloc((size_t)N_ * 4);
    int* bsum   = (int*)alloc(128 * 4);
    int* adj    = (int*)alloc((size_t)2 * E_ * 4);

    // CSR build
    hipMemsetAsync(deg, 0, (size_t)N_ * 4, stream);
    k_hist<<<(E_ + 255) / 256, 256, 0, stream>>>(edges, E_, deg);
    int nb = (N_ + 1023) / 1024;   // 98
    k_scan1<<<nb, 1024, 0, stream>>>(deg, N_, incl, bsum);
    k_scan2<<<1, 128, 0, stream>>>(bsum, nb);
    k_scan3<<<(N_ + 255) / 256, 256, 0, stream>>>(incl, deg, bsum, N_, 2 * E_, rowst, cursor);
    k_fill<<<(E_ + 255) / 256, 256, 0, stream>>>(edges, E_, cursor, adj);

    // weight + feature conversion
    k_wprep<<<(13 * 2 * 16384 + 255) / 256, 256, 0, stream>>>(W0_1, W1_1, W0_h, W1_h, wb);
    k_cvt<<<(N_ * D / 4 + 255) / 256, 256, 0, stream>>>(features, xf, N_ * D / 4);

    int gblocks = (N_ + 127) / 128;   // 782
    int ablocks = (N_ + 3) / 4;

    // layer 1: xf -> resid
    k_agg<<<ablocks, 256, 0, stream>>>(xf, rowst, adj, sb, N_);
    k_gemm<<<gblocks, 256, 0, stream>>>(xf, sb, wb, b0_1, b1_1, deg, resid, nullptr, N_, 1);

    // 12 hidden layers
    for (int h = 0; h < 12; ++h) {
        const unsigned short* in = (h == 0) ? resid : ((h & 1) ? xa : xb);
        unsigned short* outp = (h & 1) ? xb : xa;
        float* o32 = (h == 11) ? aux : nullptr;
        k_agg<<<ablocks, 256, 0, stream>>>(in, rowst, adj, sb, N_);
        k_gemm<<<gblocks, 256, 0, stream>>>(in, sb, wb + (size_t)(1 + h) * 32768,
                                            b0_h + h * 128, b1_h + h * 128, deg, outp, o32, N_, 1);
    }

    // last layer: z = resid + x12 (in xb); vertices = gconv(z), no relu
    k_addb<<<(N_ * D / 2 + 255) / 256, 256, 0, stream>>>(resid, xb, xa, N_ * D / 2);
    k_agg<<<ablocks, 256, 0, stream>>>(xa, rowst, adj, sb, N_);
    k_last<<<ablocks, 256, 0, stream>>>(xa, sb, W0_l, b0_l, W1_l, b1_l, deg, vert, N_);
}

// Round 3
// 1459.920 us; speedup vs baseline: 2.3301x; 1.1562x over previous
//
#include <hip/hip_runtime.h>
#include <hip/hip_bf16.h>

#define D 128

typedef float f32x4  __attribute__((ext_vector_type(4)));
typedef __attribute__((ext_vector_type(8))) __bf16 bh8;

__device__ inline float bf2f(unsigned short u) {
    union { unsigned int i; float f; } x; x.i = ((unsigned int)u) << 16; return x.f;
}
__device__ inline unsigned short f2bf(float f) {
    union { float f; unsigned int i; } x; x.f = f;
    return (unsigned short)((x.i + 0x7fffu + ((x.i >> 16) & 1u)) >> 16);
}
__device__ inline void acc2(unsigned int u, float& a, float& b) {
    union { unsigned int i; float f; } lo, hi;
    lo.i = u << 16; hi.i = u & 0xffff0000u;
    a += lo.f; b += hi.f;
}

// ---------------- CSR build ----------------
__global__ void k_hist(const int* __restrict__ edges, int E, int* __restrict__ deg) {
    int e = blockIdx.x * blockDim.x + threadIdx.x;
    if (e < E) {
        atomicAdd(&deg[edges[2 * e]], 1);
        atomicAdd(&deg[edges[2 * e + 1]], 1);
    }
}

__global__ void k_scan1(const int* __restrict__ deg, int n,
                        int* __restrict__ incl, int* __restrict__ bsum) {
    __shared__ int lds[1024];
    int t = threadIdx.x;
    int i = blockIdx.x * 1024 + t;
    int v = (i < n) ? deg[i] : 0;
    int cur = v;
    lds[t] = cur;
    __syncthreads();
    for (int off = 1; off < 1024; off <<= 1) {
        int add = (t >= off) ? lds[t - off] : 0;
        __syncthreads();
        cur += add;
        lds[t] = cur;
        __syncthreads();
    }
    if (i < n) incl[i] = cur;
    if (t == 1023) bsum[blockIdx.x] = cur;
}

__global__ void k_scan2(int* __restrict__ bsum, int nb) {
    __shared__ int lds[128];
    int t = threadIdx.x;
    int v = (t < nb) ? bsum[t] : 0;
    int cur = v;
    lds[t] = cur;
    __syncthreads();
    for (int off = 1; off < 128; off <<= 1) {
        int add = (t >= off) ? lds[t - off] : 0;
        __syncthreads();
        cur += add;
        lds[t] = cur;
        __syncthreads();
    }
    if (t < nb) bsum[t] = cur - v;  // exclusive
}

__global__ void k_scan3(const int* __restrict__ incl, const int* __restrict__ deg,
                        const int* __restrict__ bsum, int n, int twoE,
                        int* __restrict__ rowstart, int* __restrict__ cursor) {
    int i = blockIdx.x * blockDim.x + threadIdx.x;
    if (i < n) {
        int r = incl[i] - deg[i] + bsum[i >> 10];
        rowstart[i] = r;
        cursor[i] = r;
    }
    if (i == 0) rowstart[n] = twoE;
}

__global__ void k_fill(const int* __restrict__ edges, int E,
                       int* __restrict__ cursor, int* __restrict__ adj) {
    int e = blockIdx.x * blockDim.x + threadIdx.x;
    if (e < E) {
        int a = edges[2 * e], b = edges[2 * e + 1];
        adj[atomicAdd(&cursor[a], 1)] = b;
        adj[atomicAdd(&cursor[b], 1)] = a;
    }
}

// ---------------- weight prep: bf16, K-chunked layout ----------------
// wb[l][chunk=kk>>5][o][kk&31], kk = m*128+k (m=0: W0, m=1: W1)
__global__ void k_wprep(const float* __restrict__ W0_1, const float* __restrict__ W1_1,
                        const float* __restrict__ W0_h, const float* __restrict__ W1_h,
                        unsigned short* __restrict__ wb) {
    int idx = blockIdx.x * 256 + threadIdx.x;
    if (idx >= 13 * 2 * 128 * 128) return;
    int k = idx & 127;
    int o = (idx >> 7) & 127;
    int m = (idx >> 14) & 1;
    int l = idx >> 15;
    const float* src = (l == 0) ? (m ? W1_1 : W0_1)
                                : ((m ? W1_h : W0_h) + (size_t)(l - 1) * 16384);
    float v = src[o * 128 + k];
    int kk = m * 128 + k;
    wb[(size_t)l * 32768 + (kk >> 5) * 4096 + o * 32 + (kk & 31)] = f2bf(v);
}

// ---------------- fp32 -> bf16 convert ----------------
__global__ void k_cvt(const float* __restrict__ in, unsigned short* __restrict__ out, int n4) {
    int i = blockIdx.x * blockDim.x + threadIdx.x;
    if (i >= n4) return;
    f32x4 v = *(const f32x4*)&in[(size_t)i * 4];
    unsigned short u[4];
    #pragma unroll
    for (int j = 0; j < 4; ++j) u[j] = f2bf(v[j]);
    *(uint2*)&out[(size_t)i * 4] = *(uint2*)u;
}

// ---------------- bf16 add: c = a + b ----------------
__global__ void k_addb(const unsigned short* __restrict__ a, const unsigned short* __restrict__ b,
                       unsigned short* __restrict__ c, int n2) {
    int i = blockIdx.x * blockDim.x + threadIdx.x;
    if (i >= n2) return;
    unsigned int ua = ((const unsigned int*)a)[i];
    unsigned int ub = ((const unsigned int*)b)[i];
    union { unsigned int i; float f; } la, ha, lb, hb;
    la.i = ua << 16; ha.i = ua & 0xffff0000u;
    lb.i = ub << 16; hb.i = ub & 0xffff0000u;
    unsigned int out = ((unsigned int)f2bf(ha.f + hb.f) << 16) | f2bf(la.f + lb.f);
    ((unsigned int*)c)[i] = out;
}

// ---------------- neighbor aggregation (bf16 in/out, fp32 accum) ----------------
// wave per node; unroll-by-4 => 4 independent 256B row-loads in flight
__global__ __launch_bounds__(256) void k_agg(
    const unsigned short* __restrict__ x, const int* __restrict__ rowstart,
    const int* __restrict__ adj, unsigned short* __restrict__ s, int n) {
    int node = blockIdx.x * 4 + (threadIdx.x >> 6);
    int lane = threadIdx.x & 63;
    if (node >= n) return;
    int r0 = rowstart[node], r1 = rowstart[node + 1];
    float a0 = 0.f, a1 = 0.f, b0 = 0.f, b1 = 0.f;
    float c0 = 0.f, c1 = 0.f, d0 = 0.f, d1 = 0.f;
    int p = r0;
    int end4 = r0 + ((r1 - r0) & ~3);
    for (; p < end4; p += 4) {
        int j0 = adj[p], j1 = adj[p + 1], j2 = adj[p + 2], j3 = adj[p + 3];
        unsigned int u0 = *(const unsigned int*)&x[(size_t)j0 * D + lane * 2];
        unsigned int u1 = *(const unsigned int*)&x[(size_t)j1 * D + lane * 2];
        unsigned int u2 = *(const unsigned int*)&x[(size_t)j2 * D + lane * 2];
        unsigned int u3 = *(const unsigned int*)&x[(size_t)j3 * D + lane * 2];
        acc2(u0, a0, a1);
        acc2(u1, b0, b1);
        acc2(u2, c0, c1);
        acc2(u3, d0, d1);
    }
    for (; p < r1; ++p) {
        int j = adj[p];
        unsigned int u = *(const unsigned int*)&x[(size_t)j * D + lane * 2];
        acc2(u, a0, a1);
    }
    float f0 = (a0 + b0) + (c0 + d0);
    float f1 = (a1 + b1) + (c1 + d1);
    unsigned int out = ((unsigned int)f2bf(f1) << 16) | f2bf(f0);
    *(unsigned int*)&s[(size_t)node * D + lane * 2] = out;
}

// ---------------- MFMA GEMM: out[i][o] = act([x_i, s_i] @ [W0T;W1T] + b0 + deg*b1) ----------------
// 256 threads = 4 waves; block tile 128 nodes x 128 outs; K=256 in 8 chunks of 32.
// Register double-buffer: chunk k+1 global loads issued while chunk k MFMAs run.
#define ASTR 40
__global__ __launch_bounds__(256) void k_gemm(
    const unsigned short* __restrict__ x,   // [n][128] bf16
    const unsigned short* __restrict__ s,   // [n][128] bf16
    const unsigned short* __restrict__ wb,  // layer weights, chunked [8][128][32] bf16
    const float* __restrict__ b0, const float* __restrict__ b1,
    const int* __restrict__ deg,
    unsigned short* __restrict__ out,       // [n][128] bf16
    float* __restrict__ out32,              // optional fp32 copy (aux), may be null
    int n, int do_relu) {
    __shared__ __align__(16) unsigned short Alds[128 * ASTR];  // 10240 B
    __shared__ __align__(16) unsigned short Blds[128 * ASTR];  // 10240 B
    int t = threadIdx.x;
    int node0 = blockIdx.x * 128;
    int lane = t & 63;
    int wave = t >> 6;
    int wm = (wave & 1) * 64;
    int wn = (wave >> 1) * 64;
    int mlane = lane & 15;
    int quad = lane >> 4;

    int rowA[2], segA[2];
    #pragma unroll
    for (int p = 0; p < 2; ++p) {
        int c = p * 256 + t;
        rowA[p] = c >> 2;
        segA[p] = (c & 3) * 8;
    }

    f32x4 acc[4][4];
    #pragma unroll
    for (int i = 0; i < 4; ++i)
        #pragma unroll
        for (int j = 0; j < 4; ++j) acc[i][j] = (f32x4){0.f, 0.f, 0.f, 0.f};

    uint4 ra[2], rb[2];
    auto fetch = [&](int kc) {
        const unsigned short* srcA = (kc < 4) ? x : s;
        int kbase = (kc & 3) * 32;
        #pragma unroll
        for (int p = 0; p < 2; ++p) {
            int g = node0 + rowA[p];
            uint4 v = {0u, 0u, 0u, 0u};
            if (g < n) v = *(const uint4*)&srcA[(size_t)g * D + kbase + segA[p]];
            ra[p] = v;
            rb[p] = *(const uint4*)&wb[(size_t)kc * 4096 + (size_t)(p * 256 + t) * 8];
        }
    };

    fetch(0);
    for (int kc = 0; kc < 8; ++kc) {
        __syncthreads();   // previous chunk's frag reads complete
        #pragma unroll
        for (int p = 0; p < 2; ++p) {
            *(uint4*)&Alds[rowA[p] * ASTR + segA[p]] = ra[p];
            *(uint4*)&Blds[rowA[p] * ASTR + segA[p]] = rb[p];
        }
        __syncthreads();
        if (kc < 7) fetch(kc + 1);   // overlap next-chunk loads with MFMA below

        bh8 af[4], bf_[4];
        #pragma unroll
        for (int i = 0; i < 4; ++i)
            af[i] = *(const bh8*)&Alds[(wm + i * 16 + mlane) * ASTR + quad * 8];
        #pragma unroll
        for (int j = 0; j < 4; ++j)
            bf_[j] = *(const bh8*)&Blds[(wn + j * 16 + mlane) * ASTR + quad * 8];
        #pragma unroll
        for (int i = 0; i < 4; ++i)
            #pragma unroll
            for (int j = 0; j < 4; ++j)
                acc[i][j] = __builtin_amdgcn_mfma_f32_16x16x32_bf16(af[i], bf_[j], acc[i][j], 0, 0, 0);
    }

    // epilogue: bias + deg*b1 + relu, direct stores
    #pragma unroll
    for (int i = 0; i < 4; ++i) {
        int m = wm + i * 16 + quad * 4;
        #pragma unroll
        for (int j = 0; j < 4; ++j) {
            int nn = wn + j * 16 + mlane;
            float b0v = b0[nn], b1v = b1[nn];
            #pragma unroll
            for (int r = 0; r < 4; ++r) {
                int g = node0 + m + r;
                if (g < n) {
                    float dg = (float)deg[g];
                    float val = acc[i][j][r] + b0v + dg * b1v;
                    if (do_relu) val = fmaxf(val, 0.f);
                    out[(size_t)g * D + nn] = f2bf(val);
                    if (out32) out32[(size_t)g * D + nn] = val;
                }
            }
        }
    }
}

// ---------------- last layer (D_out = 3, fp32 out, no relu) ----------------
__global__ void k_last(const unsigned short* __restrict__ z, const unsigned short* __restrict__ sz,
                       const float* __restrict__ W0, const float* __restrict__ b0,
                       const float* __restrict__ W1, const float* __restrict__ b1,
                       const int* __restrict__ deg, float* __restrict__ vert, int n) {
    int t = threadIdx.x;
    int lane = t & 63;
    int node = blockIdx.x * 4 + (t >> 6);
    if (node >= n) return;
    float z0 = bf2f(z[(size_t)node * D + lane]), z1 = bf2f(z[(size_t)node * D + 64 + lane]);
    float s0 = bf2f(sz[(size_t)node * D + lane]), s1 = bf2f(sz[(size_t)node * D + 64 + lane]);
    float dg = (float)deg[node];
    #pragma unroll
    for (int o = 0; o < 3; ++o) {
        float p = z0 * W0[o * D + lane] + z1 * W0[o * D + 64 + lane]
                + s0 * W1[o * D + lane] + s1 * W1[o * D + 64 + lane];
        for (int off = 32; off > 0; off >>= 1) p += __shfl_down(p, off);
        if (lane == 0) vert[(size_t)node * 3 + o] = p + b0[o] + dg * b1[o];
    }
}

extern "C" void kernel_launch(void* const* d_in, const int* in_sizes, int n_in,
                              void* d_out, int out_size, void* d_ws, size_t ws_size,
                              hipStream_t stream) {
    const float* features = (const float*)d_in[0];
    const int*   edges    = (const int*)d_in[1];
    const float* W0_1 = (const float*)d_in[2];
    const float* b0_1 = (const float*)d_in[3];
    const float* W1_1 = (const float*)d_in[4];
    const float* b1_1 = (const float*)d_in[5];
    const float* W0_h = (const float*)d_in[6];
    const float* b0_h = (const float*)d_in[7];
    const float* W1_h = (const float*)d_in[8];
    const float* b1_h = (const float*)d_in[9];
    const float* W0_l = (const float*)d_in[10];
    const float* b0_l = (const float*)d_in[11];
    const float* W1_l = (const float*)d_in[12];
    const float* b1_l = (const float*)d_in[13];

    const int N_ = 100000, E_ = 300000;
    float* vert = (float*)d_out;                    // N*3
    float* aux  = (float*)d_out + (size_t)N_ * 3;   // N*128 fp32

    char* w = (char*)d_ws;
    auto alloc = [&](size_t bytes) {
        char* p = w;
        w += (bytes + 255) & ~(size_t)255;
        return p;
    };
    unsigned short* wb    = (unsigned short*)alloc((size_t)13 * 32768 * 2);
    unsigned short* xf    = (unsigned short*)alloc((size_t)N_ * D * 2);
    unsigned short* resid = (unsigned short*)alloc((size_t)N_ * D * 2);
    unsigned short* xa    = (unsigned short*)alloc((size_t)N_ * D * 2);
    unsigned short* xb    = (unsigned short*)alloc((size_t)N_ * D * 2);
    unsigned short* sb    = (unsigned short*)alloc((size_t)N_ * D * 2);
    int* deg    = (int*)alloc((size_t)N_ * 4);
    int* incl   = (int*)alloc((size_t)N_ * 4);
    int* rowst  = (int*)alloc((size_t)(N_ + 1) * 4);
    int* cursor = (int*)alloc((size_t)N_ * 4);
    int* bsum   = (int*)alloc(128 * 4);
    int* adj    = (int*)alloc((size_t)2 * E_ * 4);

    // CSR build
    hipMemsetAsync(deg, 0, (size_t)N_ * 4, stream);
    k_hist<<<(E_ + 255) / 256, 256, 0, stream>>>(edges, E_, deg);
    int nb = (N_ + 1023) / 1024;   // 98
    k_scan1<<<nb, 1024, 0, stream>>>(deg, N_, incl, bsum);
    k_scan2<<<1, 128, 0, stream>>>(bsum, nb);
    k_scan3<<<(N_ + 255) / 256, 256, 0, stream>>>(incl, deg, bsum, N_, 2 * E_, rowst, cursor);
    k_fill<<<(E_ + 255) / 256, 256, 0, stream>>>(edges, E_, cursor, adj);

    // weight + feature conversion
    k_wprep<<<(13 * 2 * 16384 + 255) / 256, 256, 0, stream>>>(W0_1, W1_1, W0_h, W1_h, wb);
    k_cvt<<<(N_ * D / 4 + 255) / 256, 256, 0, stream>>>(features, xf, N_ * D / 4);

    int gblocks = (N_ + 127) / 128;   // 782
    int ablocks = (N_ + 3) / 4;

    // layer 1: xf -> resid
    k_agg<<<ablocks, 256, 0, stream>>>(xf, rowst, adj, sb, N_);
    k_gemm<<<gblocks, 256, 0, stream>>>(xf, sb, wb, b0_1, b1_1, deg, resid, nullptr, N_, 1);

    // 12 hidden layers
    for (int h = 0; h < 12; ++h) {
        const unsigned short* in = (h == 0) ? resid : ((h & 1) ? xa : xb);
        unsigned short* outp = (h & 1) ? xb : xa;
        float* o32 = (h == 11) ? aux : nullptr;
        k_agg<<<ablocks, 256, 0, stream>>>(in, rowst, adj, sb, N_);
        k_gemm<<<gblocks, 256, 0, stream>>>(in, sb, wb + (size_t)(1 + h) * 32768,
                                            b0_h + h * 128, b1_h + h * 128, deg, outp, o32, N_, 1);
    }

    // last layer: z = resid + x12 (in xb); vertices = gconv(z), no relu
    k_addb<<<(N_ * D / 2 + 255) / 256, 256, 0, stream>>>(resid, xb, xa, N_ * D / 2);
    k_agg<<<ablocks, 256, 0, stream>>>(xa, rowst, adj, sb, N_);
    k_last<<<ablocks, 256, 0, stream>>>(xa, sb, W0_l, b0_l, W1_l, b1_l, deg, vert, N_);
}

// Round 4
// 1332.348 us; speedup vs baseline: 2.5533x; 1.0957x over previous
//
#include <hip/hip_runtime.h>
#include <hip/hip_bf16.h>

#define D 128

typedef float f32x4  __attribute__((ext_vector_type(4)));
typedef __attribute__((ext_vector_type(8))) __bf16 bh8;

__device__ inline float bf2f(unsigned short u) {
    union { unsigned int i; float f; } x; x.i = ((unsigned int)u) << 16; return x.f;
}
__device__ inline unsigned short f2bf(float f) {
    union { float f; unsigned int i; } x; x.f = f;
    return (unsigned short)((x.i + 0x7fffu + ((x.i >> 16) & 1u)) >> 16);
}
__device__ inline void acc2(unsigned int u, float& a, float& b) {
    union { unsigned int i; float f; } lo, hi;
    lo.i = u << 16; hi.i = u & 0xffff0000u;
    a += lo.f; b += hi.f;
}

// ---------------- CSR build ----------------
__global__ void k_hist(const int* __restrict__ edges, int E, int* __restrict__ deg) {
    int e = blockIdx.x * blockDim.x + threadIdx.x;
    if (e < E) {
        atomicAdd(&deg[edges[2 * e]], 1);
        atomicAdd(&deg[edges[2 * e + 1]], 1);
    }
}

__global__ void k_scan1(const int* __restrict__ deg, int n,
                        int* __restrict__ incl, int* __restrict__ bsum) {
    __shared__ int lds[1024];
    int t = threadIdx.x;
    int i = blockIdx.x * 1024 + t;
    int v = (i < n) ? deg[i] : 0;
    int cur = v;
    lds[t] = cur;
    __syncthreads();
    for (int off = 1; off < 1024; off <<= 1) {
        int add = (t >= off) ? lds[t - off] : 0;
        __syncthreads();
        cur += add;
        lds[t] = cur;
        __syncthreads();
    }
    if (i < n) incl[i] = cur;
    if (t == 1023) bsum[blockIdx.x] = cur;
}

__global__ void k_scan2(int* __restrict__ bsum, int nb) {
    __shared__ int lds[128];
    int t = threadIdx.x;
    int v = (t < nb) ? bsum[t] : 0;
    int cur = v;
    lds[t] = cur;
    __syncthreads();
    for (int off = 1; off < 128; off <<= 1) {
        int add = (t >= off) ? lds[t - off] : 0;
        __syncthreads();
        cur += add;
        lds[t] = cur;
        __syncthreads();
    }
    if (t < nb) bsum[t] = cur - v;  // exclusive
}

__global__ void k_scan3(const int* __restrict__ incl, const int* __restrict__ deg,
                        const int* __restrict__ bsum, int n, int twoE,
                        int* __restrict__ rowstart, int* __restrict__ cursor) {
    int i = blockIdx.x * blockDim.x + threadIdx.x;
    if (i < n) {
        int r = incl[i] - deg[i] + bsum[i >> 10];
        rowstart[i] = r;
        cursor[i] = r;
    }
    if (i == 0) rowstart[n] = twoE;
}

__global__ void k_fill(const int* __restrict__ edges, int E,
                       int* __restrict__ cursor, int* __restrict__ adj) {
    int e = blockIdx.x * blockDim.x + threadIdx.x;
    if (e < E) {
        int a = edges[2 * e], b = edges[2 * e + 1];
        adj[atomicAdd(&cursor[a], 1)] = b;
        adj[atomicAdd(&cursor[b], 1)] = a;
    }
}

// ---------------- weight prep: bf16, K-chunked layout ----------------
// wb[l][chunk=kk>>5][o][kk&31], kk = m*128+k (m=0: W0, m=1: W1)
__global__ void k_wprep(const float* __restrict__ W0_1, const float* __restrict__ W1_1,
                        const float* __restrict__ W0_h, const float* __restrict__ W1_h,
                        unsigned short* __restrict__ wb) {
    int idx = blockIdx.x * 256 + threadIdx.x;
    if (idx >= 13 * 2 * 128 * 128) return;
    int k = idx & 127;
    int o = (idx >> 7) & 127;
    int m = (idx >> 14) & 1;
    int l = idx >> 15;
    const float* src = (l == 0) ? (m ? W1_1 : W0_1)
                                : ((m ? W1_h : W0_h) + (size_t)(l - 1) * 16384);
    float v = src[o * 128 + k];
    int kk = m * 128 + k;
    wb[(size_t)l * 32768 + (kk >> 5) * 4096 + o * 32 + (kk & 31)] = f2bf(v);
}

// ---------------- fp32 -> bf16 convert ----------------
__global__ void k_cvt(const float* __restrict__ in, unsigned short* __restrict__ out, int n4) {
    int i = blockIdx.x * blockDim.x + threadIdx.x;
    if (i >= n4) return;
    f32x4 v = *(const f32x4*)&in[(size_t)i * 4];
    unsigned short u[4];
    #pragma unroll
    for (int j = 0; j < 4; ++j) u[j] = f2bf(v[j]);
    *(uint2*)&out[(size_t)i * 4] = *(uint2*)u;
}

// ---------------- bf16 add: c = a + b ----------------
__global__ void k_addb(const unsigned short* __restrict__ a, const unsigned short* __restrict__ b,
                       unsigned short* __restrict__ c, int n2) {
    int i = blockIdx.x * blockDim.x + threadIdx.x;
    if (i >= n2) return;
    unsigned int ua = ((const unsigned int*)a)[i];
    unsigned int ub = ((const unsigned int*)b)[i];
    union { unsigned int i; float f; } la, ha, lb, hb;
    la.i = ua << 16; ha.i = ua & 0xffff0000u;
    lb.i = ub << 16; hb.i = ub & 0xffff0000u;
    unsigned int out = ((unsigned int)f2bf(ha.f + hb.f) << 16) | f2bf(la.f + lb.f);
    ((unsigned int*)c)[i] = out;
}

// ---------------- neighbor aggregation (bf16 in/out, fp32 accum) ----------------
// wave per node; one vector adj load + shfl broadcast => up to 8 row-loads in flight
__global__ __launch_bounds__(256) void k_agg(
    const unsigned short* __restrict__ x, const int* __restrict__ rowstart,
    const int* __restrict__ adj, unsigned short* __restrict__ s, int n) {
    int node = blockIdx.x * 4 + (threadIdx.x >> 6);
    int lane = threadIdx.x & 63;
    if (node >= n) return;
    int r0 = rowstart[node], r1 = rowstart[node + 1];
    float a[8], b[8];
    #pragma unroll
    for (int k = 0; k < 8; ++k) { a[k] = 0.f; b[k] = 0.f; }
    for (int p = r0; p < r1; p += 8) {
        int q = p + (lane & 7);
        int idx = (q < r1) ? adj[q] : 0;
        unsigned int u[8];
        #pragma unroll
        for (int k = 0; k < 8; ++k) {
            int j = __shfl(idx, k);
            u[k] = *(const unsigned int*)&x[(size_t)j * D + lane * 2];
        }
        #pragma unroll
        for (int k = 0; k < 8; ++k)
            if (p + k < r1) acc2(u[k], a[k], b[k]);
    }
    float f0 = ((a[0] + a[1]) + (a[2] + a[3])) + ((a[4] + a[5]) + (a[6] + a[7]));
    float f1 = ((b[0] + b[1]) + (b[2] + b[3])) + ((b[4] + b[5]) + (b[6] + b[7]));
    unsigned int out = ((unsigned int)f2bf(f1) << 16) | f2bf(f0);
    *(unsigned int*)&s[(size_t)node * D + lane * 2] = out;
}

// ---------------- MFMA GEMM: out[i][o] = act([x_i, s_i] @ [W0T;W1T] + b0 + deg*b1) ----------------
// 256 threads = 4 waves; block tile 128 nodes x 128 outs; K=256 in 8 chunks of 32.
// Epilogue transposes through LDS for fully-coalesced uint4 stores.
#define ASTR 40
#define OSTR 136
__global__ __launch_bounds__(256) void k_gemm(
    const unsigned short* __restrict__ x,   // [n][128] bf16
    const unsigned short* __restrict__ s,   // [n][128] bf16
    const unsigned short* __restrict__ wb,  // layer weights, chunked [8][128][32] bf16
    const float* __restrict__ b0, const float* __restrict__ b1,
    const int* __restrict__ deg,
    unsigned short* __restrict__ out,       // [n][128] bf16
    float* __restrict__ out32,              // optional fp32 copy (aux), may be null
    int n, int do_relu) {
    __shared__ __align__(16) unsigned short LDS[128 * OSTR];  // 34816 B
    unsigned short* Alds = LDS;                 // 128*ASTR shorts
    unsigned short* Blds = LDS + 128 * ASTR;    // 128*ASTR shorts
    int t = threadIdx.x;
    int node0 = blockIdx.x * 128;
    int lane = t & 63;
    int wave = t >> 6;
    int wm = (wave & 1) * 64;
    int wn = (wave >> 1) * 64;
    int mlane = lane & 15;
    int quad = lane >> 4;

    int rowA[2], segA[2];
    #pragma unroll
    for (int p = 0; p < 2; ++p) {
        int c = p * 256 + t;
        rowA[p] = c >> 2;
        segA[p] = (c & 3) * 8;
    }

    f32x4 acc[4][4];
    #pragma unroll
    for (int i = 0; i < 4; ++i)
        #pragma unroll
        for (int j = 0; j < 4; ++j) acc[i][j] = (f32x4){0.f, 0.f, 0.f, 0.f};

    uint4 ra[2], rb[2];
    auto fetch = [&](int kc) {
        const unsigned short* srcA = (kc < 4) ? x : s;
        int kbase = (kc & 3) * 32;
        #pragma unroll
        for (int p = 0; p < 2; ++p) {
            int g = node0 + rowA[p];
            uint4 v = {0u, 0u, 0u, 0u};
            if (g < n) v = *(const uint4*)&srcA[(size_t)g * D + kbase + segA[p]];
            ra[p] = v;
            rb[p] = *(const uint4*)&wb[(size_t)kc * 4096 + (size_t)(p * 256 + t) * 8];
        }
    };

    fetch(0);
    for (int kc = 0; kc < 8; ++kc) {
        __syncthreads();   // previous chunk's frag reads complete
        #pragma unroll
        for (int p = 0; p < 2; ++p) {
            *(uint4*)&Alds[rowA[p] * ASTR + segA[p]] = ra[p];
            *(uint4*)&Blds[rowA[p] * ASTR + segA[p]] = rb[p];
        }
        __syncthreads();
        if (kc < 7) fetch(kc + 1);   // overlap next-chunk loads with MFMA below

        bh8 af[4], bf_[4];
        #pragma unroll
        for (int i = 0; i < 4; ++i)
            af[i] = *(const bh8*)&Alds[(wm + i * 16 + mlane) * ASTR + quad * 8];
        #pragma unroll
        for (int j = 0; j < 4; ++j)
            bf_[j] = *(const bh8*)&Blds[(wn + j * 16 + mlane) * ASTR + quad * 8];
        #pragma unroll
        for (int i = 0; i < 4; ++i)
            #pragma unroll
            for (int j = 0; j < 4; ++j)
                acc[i][j] = __builtin_amdgcn_mfma_f32_16x16x32_bf16(af[i], bf_[j], acc[i][j], 0, 0, 0);
    }

    // ---- epilogue: bias + deg*b1 + relu -> LDS transpose -> coalesced stores ----
    __syncthreads();   // done with A/B staging buffers; reuse LDS as Olds
    #pragma unroll
    for (int i = 0; i < 4; ++i) {
        int mrow = wm + i * 16 + quad * 4;
        #pragma unroll
        for (int j = 0; j < 4; ++j) {
            int nn = wn + j * 16 + mlane;
            float b0v = b0[nn], b1v = b1[nn];
            #pragma unroll
            for (int r = 0; r < 4; ++r) {
                int g = node0 + mrow + r;
                float dg = (g < n) ? (float)deg[g] : 0.f;
                float val = acc[i][j][r] + b0v + dg * b1v;
                if (do_relu) val = fmaxf(val, 0.f);
                LDS[(mrow + r) * OSTR + nn] = f2bf(val);
            }
        }
    }
    __syncthreads();
    // bf16 store: 8 passes, 16 lanes x 16B = one full 256B node row per 16 threads
    #pragma unroll
    for (int pass = 0; pass < 8; ++pass) {
        int row = pass * 16 + (t >> 4);
        int seg = (t & 15) * 8;
        int g = node0 + row;
        if (g < n)
            *(uint4*)&out[(size_t)g * D + seg] = *(const uint4*)&LDS[row * OSTR + seg];
    }
    if (out32) {
        #pragma unroll
        for (int pass = 0; pass < 16; ++pass) {
            int row = pass * 8 + (t >> 5);
            int seg = (t & 31) * 4;
            int g = node0 + row;
            if (g < n) {
                f32x4 v;
                #pragma unroll
                for (int j = 0; j < 4; ++j) v[j] = bf2f(LDS[row * OSTR + seg + j]);
                *(f32x4*)&out32[(size_t)g * D + seg] = v;
            }
        }
    }
}

// ---------------- last layer (D_out = 3, fp32 out, no relu) ----------------
__global__ void k_last(const unsigned short* __restrict__ z, const unsigned short* __restrict__ sz,
                       const float* __restrict__ W0, const float* __restrict__ b0,
                       const float* __restrict__ W1, const float* __restrict__ b1,
                       const int* __restrict__ deg, float* __restrict__ vert, int n) {
    int t = threadIdx.x;
    int lane = t & 63;
    int node = blockIdx.x * 4 + (t >> 6);
    if (node >= n) return;
    float z0 = bf2f(z[(size_t)node * D + lane]), z1 = bf2f(z[(size_t)node * D + 64 + lane]);
    float s0 = bf2f(sz[(size_t)node * D + lane]), s1 = bf2f(sz[(size_t)node * D + 64 + lane]);
    float dg = (float)deg[node];
    #pragma unroll
    for (int o = 0; o < 3; ++o) {
        float p = z0 * W0[o * D + lane] + z1 * W0[o * D + 64 + lane]
                + s0 * W1[o * D + lane] + s1 * W1[o * D + 64 + lane];
        for (int off = 32; off > 0; off >>= 1) p += __shfl_down(p, off);
        if (lane == 0) vert[(size_t)node * 3 + o] = p + b0[o] + dg * b1[o];
    }
}

extern "C" void kernel_launch(void* const* d_in, const int* in_sizes, int n_in,
                              void* d_out, int out_size, void* d_ws, size_t ws_size,
                              hipStream_t stream) {
    const float* features = (const float*)d_in[0];
    const int*   edges    = (const int*)d_in[1];
    const float* W0_1 = (const float*)d_in[2];
    const float* b0_1 = (const float*)d_in[3];
    const float* W1_1 = (const float*)d_in[4];
    const float* b1_1 = (const float*)d_in[5];
    const float* W0_h = (const float*)d_in[6];
    const float* b0_h = (const float*)d_in[7];
    const float* W1_h = (const float*)d_in[8];
    const float* b1_h = (const float*)d_in[9];
    const float* W0_l = (const float*)d_in[10];
    const float* b0_l = (const float*)d_in[11];
    const float* W1_l = (const float*)d_in[12];
    const float* b1_l = (const float*)d_in[13];

    const int N_ = 100000, E_ = 300000;
    float* vert = (float*)d_out;                    // N*3
    float* aux  = (float*)d_out + (size_t)N_ * 3;   // N*128 fp32

    char* w = (char*)d_ws;
    auto alloc = [&](size_t bytes) {
        char* p = w;
        w += (bytes + 255) & ~(size_t)255;
        return p;
    };
    unsigned short* wb    = (unsigned short*)alloc((size_t)13 * 32768 * 2);
    unsigned short* xf    = (unsigned short*)alloc((size_t)N_ * D * 2);
    unsigned short* resid = (unsigned short*)alloc((size_t)N_ * D * 2);
    unsigned short* xa    = (unsigned short*)alloc((size_t)N_ * D * 2);
    unsigned short* xb    = (unsigned short*)alloc((size_t)N_ * D * 2);
    unsigned short* sb    = (unsigned short*)alloc((size_t)N_ * D * 2);
    int* deg    = (int*)alloc((size_t)N_ * 4);
    int* incl   = (int*)alloc((size_t)N_ * 4);
    int* rowst  = (int*)alloc((size_t)(N_ + 1) * 4);
    int* cursor = (int*)alloc((size_t)N_ * 4);
    int* bsum   = (int*)alloc(128 * 4);
    int* adj    = (int*)alloc((size_t)2 * E_ * 4);

    // CSR build
    hipMemsetAsync(deg, 0, (size_t)N_ * 4, stream);
    k_hist<<<(E_ + 255) / 256, 256, 0, stream>>>(edges, E_, deg);
    int nb = (N_ + 1023) / 1024;   // 98
    k_scan1<<<nb, 1024, 0, stream>>>(deg, N_, incl, bsum);
    k_scan2<<<1, 128, 0, stream>>>(bsum, nb);
    k_scan3<<<(N_ + 255) / 256, 256, 0, stream>>>(incl, deg, bsum, N_, 2 * E_, rowst, cursor);
    k_fill<<<(E_ + 255) / 256, 256, 0, stream>>>(edges, E_, cursor, adj);

    // weight + feature conversion
    k_wprep<<<(13 * 2 * 16384 + 255) / 256, 256, 0, stream>>>(W0_1, W1_1, W0_h, W1_h, wb);
    k_cvt<<<(N_ * D / 4 + 255) / 256, 256, 0, stream>>>(features, xf, N_ * D / 4);

    int gblocks = (N_ + 127) / 128;   // 782
    int ablocks = (N_ + 3) / 4;

    // layer 1: xf -> resid
    k_agg<<<ablocks, 256, 0, stream>>>(xf, rowst, adj, sb, N_);
    k_gemm<<<gblocks, 256, 0, stream>>>(xf, sb, wb, b0_1, b1_1, deg, resid, nullptr, N_, 1);

    // 12 hidden layers
    for (int h = 0; h < 12; ++h) {
        const unsigned short* in = (h == 0) ? resid : ((h & 1) ? xa : xb);
        unsigned short* outp = (h & 1) ? xb : xa;
        float* o32 = (h == 11) ? aux : nullptr;
        k_agg<<<ablocks, 256, 0, stream>>>(in, rowst, adj, sb, N_);
        k_gemm<<<gblocks, 256, 0, stream>>>(in, sb, wb + (size_t)(1 + h) * 32768,
                                            b0_h + h * 128, b1_h + h * 128, deg, outp, o32, N_, 1);
    }

    // last layer: z = resid + x12 (in xb); vertices = gconv(z), no relu
    k_addb<<<(N_ * D / 2 + 255) / 256, 256, 0, stream>>>(resid, xb, xa, N_ * D / 2);
    k_agg<<<ablocks, 256, 0, stream>>>(xa, rowst, adj, sb, N_);
    k_last<<<ablocks, 256, 0, stream>>>(xa, sb, W0_l, b0_l, W1_l, b1_l, deg, vert, N_);
}